// Round 13
// baseline (240.259 us; speedup 1.0000x reference)
//
#include <hip/hip_runtime.h>

#define BB 2
#define SS 2048
#define DD 1024
#define HH 16
#define DKK 64

typedef __attribute__((ext_vector_type(8))) short short8;
typedef __attribute__((ext_vector_type(4))) float floatx4;

__device__ inline float bf2f(ushort u) {
    union { unsigned int i; float f; } x; x.i = ((unsigned int)u) << 16; return x.f;
}
__device__ inline ushort f2bf(float f) {
    union { float f; unsigned int i; } x; x.f = f;
    unsigned int r = x.i + 0x7fff + ((x.i >> 16) & 1);
    return (ushort)(r >> 16);
}
__device__ inline void async_cp16(const ushort* g, ushort* l) {
    __builtin_amdgcn_global_load_lds(
        (const __attribute__((address_space(1))) unsigned int*)g,
        (__attribute__((address_space(3))) unsigned int*)l, 16, 0, 0);
}
// pack two f32 -> one dword of 2 bf16 (RNE), hw instruction
__device__ inline unsigned int cvt_pk_bf16(float lo, float hi) {
    unsigned int r;
    asm("v_cvt_pk_bf16_f32 %0, %1, %2" : "=v"(r) : "v"(lo), "v"(hi));
    return r;
}
// {a,b}: a.q2<->b.q0, a.q3<->b.q1  (16-lane groups = quads)
__device__ inline void swap32(unsigned int& a, unsigned int& b) {
    asm("v_permlane32_swap_b32 %0, %1" : "+v"(a), "+v"(b));
}
// {a,b}: a.q1<->b.q0, a.q3<->b.q2
__device__ inline void swap16(unsigned int& a, unsigned int& b) {
    asm("v_permlane16_swap_b32 %0, %1" : "+v"(a), "+v"(b));
}

// ---------- weight transpose+cast: Wt[n][k] = bf16(W[k][n]), 4 mats ----------
__global__ __launch_bounds__(256) void cvt_w4(const float* __restrict__ w0,
                                              const float* __restrict__ w1,
                                              const float* __restrict__ w2,
                                              const float* __restrict__ w3,
                                              ushort* __restrict__ o0,
                                              ushort* __restrict__ o1,
                                              ushort* __restrict__ o2,
                                              ushort* __restrict__ o3) {
    __shared__ ushort t[32][33];
    int z = blockIdx.z;
    const float* in = (z == 0) ? w0 : (z == 1) ? w1 : (z == 2) ? w2 : w3;
    ushort* out = (z == 0) ? o0 : (z == 1) ? o1 : (z == 2) ? o2 : o3;
    int bx = blockIdx.x, by = blockIdx.y;
    int tx = threadIdx.x & 31, ty = threadIdx.x >> 5;
    for (int i = ty; i < 32; i += 8)
        t[i][tx] = f2bf(in[(size_t)(by * 32 + i) * DD + bx * 32 + tx]);
    __syncthreads();
    for (int i = ty; i < 32; i += 8)
        out[(size_t)(bx * 32 + i) * DD + by * 32 + tx] = t[tx][i];
}

// ---------- fused Q/K/V projection GEMM: fp32 X inputs, 128x128, BK=32 -------
// cvt_qkv deleted: A reg-staged (float4 -> cvt_pk_bf16 -> swizzled ds_write),
// B via gload_lds + pre-swizzled source. Counted waits only (R8 lesson):
// in-loop vmcnt(6) drains just B(t); writeA's compiler wait is vmcnt(2)
// (A issued BEFORE B so B(t+1) stays in flight); lgkmcnt(0) before end bar.
__global__ __launch_bounds__(256, 3) void gemm_qkv(const float* __restrict__ Xq,
                                                   const float* __restrict__ Xk,
                                                   const float* __restrict__ Xv,
                                                   const ushort* __restrict__ WtQ,
                                                   const ushort* __restrict__ WtK,
                                                   const ushort* __restrict__ WtV,
                                                   const float* __restrict__ bq,
                                                   const float* __restrict__ bk,
                                                   const float* __restrict__ bv,
                                                   ushort* __restrict__ qh,
                                                   ushort* __restrict__ kh,
                                                   ushort* __restrict__ vt) {
    constexpr int K = 1024;
    constexpr int NKT = 32;
    __shared__ ushort smem[16384];           // 32 KB: 2 slots x (A 4096 + B 4096)

    int lin = blockIdx.x + ((blockIdx.y + (blockIdx.z << 5)) << 3);
    int wid = (lin & 7) * 96 + (lin >> 3);
    int z = wid >> 8;
    int rem = wid & 255;
    int byy = rem >> 3, bxx = rem & 7;
    int rowBase = byy * 128, colBase = bxx * 128;

    const float*  Ag = (z == 0) ? Xq : (z == 1) ? Xk : Xv;
    const ushort* Bg = (z == 0) ? WtQ : (z == 1) ? WtK : WtV;
    const float* bias = (z == 0) ? bq : (z == 1) ? bk : bv;
    ushort* outp = (z == 0) ? qh : (z == 1) ? kh : vt;

    int tid = threadIdx.x;
    int wave = tid >> 6, lane = tid & 63, quad = lane >> 4, l15 = lane & 15;
    int wm = wave >> 1, wn = wave & 1;

    // A reg-staging: linear dest byte lb -> (row, fp32 col); write swizzled
    int rowA[2], colA[2], dstSwzA[2];
    // B staging: pre-swizzled global source, linear gload_lds dest
    size_t srcB[2];
    int dstU[2];
#pragma unroll
    for (int r = 0; r < 2; ++r) {
        int lb = r * 4096 + wave * 1024 + lane * 16;
        int sl = lb ^ (((lb >> 9) & 1) << 5);
        rowA[r] = lb >> 6;
        colA[r] = (lb & 63) >> 1;
        dstSwzA[r] = sl >> 1;
        srcB[r] = (size_t)(colBase + (sl >> 6)) * K + ((sl & 63) >> 1);
        dstU[r] = r * 2048 + wave * 512;
    }
    int aOff[4], bOff[4];
#pragma unroll
    for (int mi = 0; mi < 4; ++mi) {
        int row = wm * 64 + mi * 16 + l15;
        aOff[mi] = row * 32 + ((quad * 8) ^ (((row >> 3) & 1) << 4));
    }
#pragma unroll
    for (int ni = 0; ni < 4; ++ni) {
        int row = wn * 64 + ni * 16 + l15;
        bOff[ni] = 4096 + row * 32 + ((quad * 8) ^ (((row >> 3) & 1) << 4));
    }

    float4 fA[4];
    auto loadA = [&](int u) {                // issue FIRST (older than B glds)
#pragma unroll
        for (int r = 0; r < 2; ++r) {
            const float* p = Ag + (size_t)(rowBase + rowA[r]) * K + u * 32 + colA[r];
            fA[r * 2]     = *(const float4*)p;
            fA[r * 2 + 1] = *(const float4*)(p + 4);
        }
    };
    auto stageB = [&](int u) {
        int slot = (u & 1) << 13;
        const ushort* Bs = Bg + u * 32;
        async_cp16(Bs + srcB[0], &smem[slot + 4096 + dstU[0]]);
        async_cp16(Bs + srcB[1], &smem[slot + 4096 + dstU[1]]);
    };
    auto writeA = [&](int u) {               // compiler waits vmcnt(2) for fA
        int slot = (u & 1) << 13;
#pragma unroll
        for (int r = 0; r < 2; ++r) {
            int4 w;
            w.x = (int)cvt_pk_bf16(fA[r * 2].x,     fA[r * 2].y);
            w.y = (int)cvt_pk_bf16(fA[r * 2].z,     fA[r * 2].w);
            w.z = (int)cvt_pk_bf16(fA[r * 2 + 1].x, fA[r * 2 + 1].y);
            w.w = (int)cvt_pk_bf16(fA[r * 2 + 1].z, fA[r * 2 + 1].w);
            *(int4*)&smem[slot + dstSwzA[r]] = w;
        }
    };

    floatx4 acc[4][4] = {};
    // prologue: fully stage tile 0
    loadA(0); stageB(0);
    asm volatile("s_waitcnt vmcnt(0)" ::: "memory");
    writeA(0);
    asm volatile("s_waitcnt lgkmcnt(0)" ::: "memory");
    __builtin_amdgcn_s_barrier();

    for (int t = 0; t < NKT; ++t) {
        bool more = (t < NKT - 1);
        if (more) {
            loadA(t + 1);                    // A first (older)
            stageB(t + 1);                   // B second (newer, stays in flight)
            asm volatile("s_waitcnt vmcnt(6)" ::: "memory");   // drain B(t) only
        }
        // (t == NKT-1: nothing outstanding)
        __builtin_amdgcn_s_barrier();        // all waves: tile t ready
        __builtin_amdgcn_sched_barrier(0);
        int slot = (t & 1) << 13;
        short8 bfr[4], af[4];
#pragma unroll
        for (int ni = 0; ni < 4; ++ni)
            bfr[ni] = *(const short8*)&smem[slot + bOff[ni]];
#pragma unroll
        for (int mi = 0; mi < 4; ++mi)
            af[mi] = *(const short8*)&smem[slot + aOff[mi]];
#pragma unroll
        for (int mi = 0; mi < 4; ++mi)
#pragma unroll
            for (int ni = 0; ni < 4; ++ni)
                acc[mi][ni] = __builtin_amdgcn_mfma_f32_16x16x32_bf16(
                    af[mi], bfr[ni], acc[mi][ni], 0, 0, 0);
        __builtin_amdgcn_sched_barrier(0);
        if (more) writeA(t + 1);             // hides A latency under MFMA
        asm volatile("s_waitcnt lgkmcnt(0)" ::: "memory");     // publish ds_writes
        __builtin_amdgcn_s_barrier();        // slot reads done -> safe overwrite
    }

    float bvv[4];
#pragma unroll
    for (int ni = 0; ni < 4; ++ni)
        bvv[ni] = bias[colBase + wn * 64 + ni * 16 + l15];
    if (z == 2) {
#pragma unroll
        for (int mi = 0; mi < 4; ++mi)
#pragma unroll
            for (int ni = 0; ni < 4; ++ni) {
                int col = colBase + wn * 64 + ni * 16 + l15;
                int h = col >> 6, dk = col & 63;
                int rowg = rowBase + wm * 64 + mi * 16 + quad * 4;
                int b = rowg >> 11, s = rowg & 2047;
                int2 v;
                v.x = (int)cvt_pk_bf16(acc[mi][ni][0] + bvv[ni], acc[mi][ni][1] + bvv[ni]);
                v.y = (int)cvt_pk_bf16(acc[mi][ni][2] + bvv[ni], acc[mi][ni][3] + bvv[ni]);
                *(int2*)&outp[((size_t)((b * HH + h) * DKK + dk)) * SS + s] = v;
            }
    } else {
#pragma unroll
        for (int mi = 0; mi < 4; ++mi)
#pragma unroll
            for (int ni = 0; ni < 4; ++ni) {
                int col = colBase + wn * 64 + ni * 16 + l15;
                int h = col >> 6, dk = col & 63;
#pragma unroll
                for (int i = 0; i < 4; ++i) {
                    int rowg = rowBase + wm * 64 + mi * 16 + quad * 4 + i;
                    int b = rowg >> 11, s = rowg & 2047;
                    outp[((size_t)((b * HH + h) * SS + s)) * DKK + dk] =
                        f2bf(acc[mi][ni][i] + bvv[ni]);
                }
            }
    }
}

// ---------- final GEMM: 64x128 tile, counted-vmcnt schedule, fp32 out -------
__global__ __launch_bounds__(256, 2) void gemm_fin(const ushort* __restrict__ A,
                                                   const ushort* __restrict__ Bt,
                                                   const float* __restrict__ bias,
                                                   float* __restrict__ outp) {
    constexpr int K = 1024, N = 1024, NKT = 32;
    __shared__ ushort smem[12288];           // 24 KB: 2 slots x (A 2048 + B 4096)
    int tid = threadIdx.x;
    int wave = tid >> 6, lane = tid & 63, quad = lane >> 4, l15 = lane & 15;
    int wm = wave >> 1, wn = wave & 1;

    int lin = blockIdx.x + (blockIdx.y << 3);
    int wid = (lin & 7) * 64 + (lin >> 3);
    int bx = wid & 7, by = wid >> 3;
    int rowBase = by * 64, colBase = bx * 128;

    size_t srcA; int dstA;
    {
        int lb = wave * 1024 + lane * 16;
        int sl = lb ^ (((lb >> 9) & 1) << 5);
        srcA = (size_t)(rowBase + (sl >> 6)) * K + ((sl & 63) >> 1);
        dstA = wave * 512;
    }
    size_t srcB[2]; int dstB[2];
#pragma unroll
    for (int r = 0; r < 2; ++r) {
        int lb = r * 4096 + wave * 1024 + lane * 16;
        int sl = lb ^ (((lb >> 9) & 1) << 5);
        srcB[r] = (size_t)(colBase + (sl >> 6)) * K + ((sl & 63) >> 1);
        dstB[r] = 2048 + r * 2048 + wave * 512;
    }
    int aOff[2], bOff[4];
#pragma unroll
    for (int mi = 0; mi < 2; ++mi) {
        int row = wm * 32 + mi * 16 + l15;
        aOff[mi] = row * 32 + ((quad * 8) ^ (((row >> 3) & 1) << 4));
    }
#pragma unroll
    for (int ni = 0; ni < 4; ++ni) {
        int row = wn * 64 + ni * 16 + l15;
        bOff[ni] = 2048 + row * 32 + ((quad * 8) ^ (((row >> 3) & 1) << 4));
    }

    auto stageTile = [&](int u) {
        int slot = (u & 1) * 6144;
        const ushort* As = A + u * 32;
        const ushort* Bs = Bt + u * 32;
        async_cp16(As + srcA, &smem[slot + dstA]);
        async_cp16(Bs + srcB[0], &smem[slot + dstB[0]]);
        async_cp16(Bs + srcB[1], &smem[slot + dstB[1]]);
    };

    floatx4 acc[2][4] = {};
    stageTile(0);
    for (int t = 0; t < NKT; ++t) {
        if (t < NKT - 1) {
            stageTile(t + 1);
            asm volatile("s_waitcnt vmcnt(3)" ::: "memory");
        } else {
            asm volatile("s_waitcnt vmcnt(0)" ::: "memory");
        }
        __builtin_amdgcn_s_barrier();
        __builtin_amdgcn_sched_barrier(0);
        int slot = (t & 1) * 6144;
        short8 af[2], bfr[4];
#pragma unroll
        for (int ni = 0; ni < 4; ++ni)
            bfr[ni] = *(const short8*)&smem[slot + bOff[ni]];
#pragma unroll
        for (int mi = 0; mi < 2; ++mi)
            af[mi] = *(const short8*)&smem[slot + aOff[mi]];
#pragma unroll
        for (int mi = 0; mi < 2; ++mi)
#pragma unroll
            for (int ni = 0; ni < 4; ++ni)
                acc[mi][ni] = __builtin_amdgcn_mfma_f32_16x16x32_bf16(
                    af[mi], bfr[ni], acc[mi][ni], 0, 0, 0);
        __builtin_amdgcn_sched_barrier(0);
        __builtin_amdgcn_s_barrier();
    }
    for (int mi = 0; mi < 2; ++mi)
        for (int ni = 0; ni < 4; ++ni) {
            int col = colBase + wn * 64 + ni * 16 + l15;
            float bv = bias[col];
            for (int i = 0; i < 4; ++i) {
                int row = rowBase + wm * 32 + mi * 16 + quad * 4 + i;
                outp[(size_t)row * N + col] = acc[mi][ni][i] + bv;
            }
        }
}

// ---------- flash attention v5: paired tiles + setprio + XCD-chunked KV -----
__global__ __launch_bounds__(256, 2) void flash_attn5(const ushort* __restrict__ qh,
                                                      const ushort* __restrict__ kh,
                                                      const ushort* __restrict__ vt,
                                                      ushort* __restrict__ attn) {
    constexpr int LD = 72;
    __shared__ ushort Ksm[2][64 * LD];
    __shared__ ushort Vsm[2][64 * LD];
    int tid = threadIdx.x;
    int wave = tid >> 6, lane = tid & 63, quad = lane >> 4, l15 = lane & 15;

    // bijective XCD-chunked remap of the 512-block grid
    int lin = blockIdx.x + (blockIdx.y << 4) + (blockIdx.z << 8);
    int wid = (lin & 7) * 64 + (lin >> 3);
    const int qt0 = wid & 15;
    int h = (wid >> 4) & 15;
    int b = wid >> 8;
    const int qt1 = 31 - qt0;

    const size_t headQK = ((size_t)(b * HH + h)) * SS * DKK;
    const size_t headV  = ((size_t)(b * HH + h)) * DKK * SS;
    int c0 = tid, r0 = c0 >> 3, s0 = (c0 & 7) * 8;
    int c1 = tid + 256, r1 = c1 >> 3, s1 = (c1 & 7) * 8;

    int qrow0 = qt0 * 64 + wave * 16 + l15;
    int qrow1 = qt1 * 64 + wave * 16 + l15;
    short8 q0a = *(const short8*)&qh[headQK + (size_t)qrow0 * DKK + quad * 8];
    short8 q0b = *(const short8*)&qh[headQK + (size_t)qrow0 * DKK + 32 + quad * 8];
    short8 q1a = *(const short8*)&qh[headQK + (size_t)qrow1 * DKK + quad * 8];
    short8 q1b = *(const short8*)&qh[headQK + (size_t)qrow1 * DKK + 32 + quad * 8];

    floatx4 o0[4] = {}, o1[4] = {};
    float l0 = 0.f, l1 = 0.f;
    int qsel = wave * 16 + l15;

    *(int4*)&Ksm[0][r0 * LD + s0] = *(const int4*)&kh[headQK + (size_t)r0 * DKK + s0];
    *(int4*)&Ksm[0][r1 * LD + s1] = *(const int4*)&kh[headQK + (size_t)r1 * DKK + s1];
    *(int4*)&Vsm[0][r0 * LD + s0] = *(const int4*)&vt[headV + (size_t)r0 * SS + s0];
    *(int4*)&Vsm[0][r1 * LD + s1] = *(const int4*)&vt[headV + (size_t)r1 * SS + s1];
    __syncthreads();

    for (int kt = 0; kt <= qt1; ++kt) {
        int cur = kt & 1;
        bool pre = (kt < qt1);
        bool act0 = (kt <= qt0);
        int4 kA, kB, vA, vB;
        if (pre) {
            const ushort* kp = &kh[headQK + (size_t)((kt + 1) * 64) * DKK];
            const ushort* vp = &vt[headV + (kt + 1) * 64];
            kA = *(const int4*)&kp[(size_t)r0 * DKK + s0];
            kB = *(const int4*)&kp[(size_t)r1 * DKK + s1];
            vA = *(const int4*)&vp[(size_t)r0 * SS + s0];
            vB = *(const int4*)&vp[(size_t)r1 * SS + s1];
        }
        // swapped QK^T: S^T = K · Q^T for both tiles off shared K fragments
        floatx4 sv1[4], sv0[4];
        __builtin_amdgcn_s_setprio(1);
#pragma unroll
        for (int cn = 0; cn < 4; ++cn) {
            short8 kf0 = *(const short8*)&Ksm[cur][(cn * 16 + l15) * LD + quad * 8];
            short8 kf1 = *(const short8*)&Ksm[cur][(cn * 16 + l15) * LD + 32 + quad * 8];
            floatx4 zz = {};
            zz = __builtin_amdgcn_mfma_f32_16x16x32_bf16(kf0, q1a, zz, 0, 0, 0);
            zz = __builtin_amdgcn_mfma_f32_16x16x32_bf16(kf1, q1b, zz, 0, 0, 0);
            sv1[cn] = zz;
            if (act0) {
                floatx4 y = {};
                y = __builtin_amdgcn_mfma_f32_16x16x32_bf16(kf0, q0a, y, 0, 0, 0);
                y = __builtin_amdgcn_mfma_f32_16x16x32_bf16(kf1, q0b, y, 0, 0, 0);
                sv0[cn] = y;
            }
        }
        __builtin_amdgcn_s_setprio(0);
        short8 vf[2][4];
#pragma unroll
        for (int ks = 0; ks < 2; ++ks)
#pragma unroll
            for (int n = 0; n < 4; ++n)
                vf[ks][n] = *(const short8*)&Vsm[cur][(n * 16 + l15) * LD + ks * 32 + quad * 8];

        {
            bool diag = (kt == qt1);
            unsigned int pkd[4][2];
#pragma unroll
            for (int cn = 0; cn < 4; ++cn) {
#pragma unroll
                for (int i = 0; i < 4; ++i) {
                    float p = __expf(sv1[cn][i] * 0.125f);
                    if (diag && (cn * 16 + quad * 4 + i) > qsel) p = 0.f;
                    sv1[cn][i] = p;
                    l1 += p;
                }
                pkd[cn][0] = cvt_pk_bf16(sv1[cn][0], sv1[cn][1]);
                pkd[cn][1] = cvt_pk_bf16(sv1[cn][2], sv1[cn][3]);
            }
            __builtin_amdgcn_s_setprio(1);
#pragma unroll
            for (int ks = 0; ks < 2; ++ks) {
                unsigned int a0 = pkd[ks * 2][0], b0 = pkd[ks * 2 + 1][0];
                swap32(a0, b0); swap16(a0, b0);
                unsigned int a1 = pkd[ks * 2][1], b1 = pkd[ks * 2 + 1][1];
                swap32(a1, b1); swap16(a1, b1);
                union { int4 i4; short8 s8; } u;
                u.i4 = make_int4((int)a0, (int)a1, (int)b0, (int)b1);
#pragma unroll
                for (int n = 0; n < 4; ++n)
                    o1[n] = __builtin_amdgcn_mfma_f32_16x16x32_bf16(
                        vf[ks][n], u.s8, o1[n], 0, 0, 0);
            }
            __builtin_amdgcn_s_setprio(0);
        }
        if (act0) {
            bool diag = (kt == qt0);
            unsigned int pkd[4][2];
#pragma unroll
            for (int cn = 0; cn < 4; ++cn) {
#pragma unroll
                for (int i = 0; i < 4; ++i) {
                    float p = __expf(sv0[cn][i] * 0.125f);
                    if (diag && (cn * 16 + quad * 4 + i) > qsel) p = 0.f;
                    sv0[cn][i] = p;
                    l0 += p;
                }
                pkd[cn][0] = cvt_pk_bf16(sv0[cn][0], sv0[cn][1]);
                pkd[cn][1] = cvt_pk_bf16(sv0[cn][2], sv0[cn][3]);
            }
            __builtin_amdgcn_s_setprio(1);
#pragma unroll
            for (int ks = 0; ks < 2; ++ks) {
                unsigned int a0 = pkd[ks * 2][0], b0 = pkd[ks * 2 + 1][0];
                swap32(a0, b0); swap16(a0, b0);
                unsigned int a1 = pkd[ks * 2][1], b1 = pkd[ks * 2 + 1][1];
                swap32(a1, b1); swap16(a1, b1);
                union { int4 i4; short8 s8; } u;
                u.i4 = make_int4((int)a0, (int)a1, (int)b0, (int)b1);
#pragma unroll
                for (int n = 0; n < 4; ++n)
                    o0[n] = __builtin_amdgcn_mfma_f32_16x16x32_bf16(
                        vf[ks][n], u.s8, o0[n], 0, 0, 0);
            }
            __builtin_amdgcn_s_setprio(0);
        }
        if (pre) {
            int nb = cur ^ 1;
            *(int4*)&Ksm[nb][r0 * LD + s0] = kA;
            *(int4*)&Ksm[nb][r1 * LD + s1] = kB;
            *(int4*)&Vsm[nb][r0 * LD + s0] = vA;
            *(int4*)&Vsm[nb][r1 * LD + s1] = vB;
        }
        __syncthreads();
    }
    l0 += __shfl_xor(l0, 16, 64); l0 += __shfl_xor(l0, 32, 64);
    l1 += __shfl_xor(l1, 16, 64); l1 += __shfl_xor(l1, 32, 64);
    float inv0 = 1.0f / l0, inv1 = 1.0f / l1;
    size_t rowOff0 = ((size_t)(b * SS + qt0 * 64 + wave * 16 + l15)) * DD + h * 64;
    size_t rowOff1 = ((size_t)(b * SS + qt1 * 64 + wave * 16 + l15)) * DD + h * 64;
#pragma unroll
    for (int n = 0; n < 4; ++n) {
        int dof = n * 16 + quad * 4;
        int2 v0, v1;
        v0.x = (int)cvt_pk_bf16(o0[n][0] * inv0, o0[n][1] * inv0);
        v0.y = (int)cvt_pk_bf16(o0[n][2] * inv0, o0[n][3] * inv0);
        v1.x = (int)cvt_pk_bf16(o1[n][0] * inv1, o1[n][1] * inv1);
        v1.y = (int)cvt_pk_bf16(o1[n][2] * inv1, o1[n][3] * inv1);
        *(int2*)&attn[rowOff0 + dof] = v0;
        *(int2*)&attn[rowOff1 + dof] = v1;
    }
}

extern "C" void kernel_launch(void* const* d_in, const int* in_sizes, int n_in,
                              void* d_out, int out_size, void* d_ws, size_t ws_size,
                              hipStream_t stream) {
    const float* q  = (const float*)d_in[0];
    const float* k  = (const float*)d_in[1];
    const float* v  = (const float*)d_in[2];
    // d_in[3] = causal mask (deterministic) -> not read
    const float* Wq = (const float*)d_in[4];
    const float* bq = (const float*)d_in[5];
    const float* Wk = (const float*)d_in[6];
    const float* bk = (const float*)d_in[7];
    const float* Wv = (const float*)d_in[8];
    const float* bv = (const float*)d_in[9];
    const float* Wo = (const float*)d_in[10];
    const float* bo = (const float*)d_in[11];

    // ws (40 MB): [WtQ|WtK|WtV|WtO 2MB each][attn 8][qh 8][kh 8][vt 8]
    ushort* ws   = (ushort*)d_ws;
    ushort* WtQ  = ws;
    ushort* WtK  = WtQ + (1u << 20);
    ushort* WtV  = WtK + (1u << 20);
    ushort* WtO  = WtV + (1u << 20);
    ushort* attn = WtO + (1u << 20);
    ushort* qh   = attn + (4u << 20);
    ushort* kh   = qh + (4u << 20);
    ushort* vt   = kh + (4u << 20);

    cvt_w4<<<dim3(32, 32, 4), 256, 0, stream>>>(Wq, Wk, Wv, Wo,
                                                WtQ, WtK, WtV, WtO);

    gemm_qkv<<<dim3(8, 32, 3), 256, 0, stream>>>(q, k, v, WtQ, WtK, WtV,
                                                 bq, bk, bv, qh, kh, vt);

    flash_attn5<<<dim3(16, 16, 2), 256, 0, stream>>>(qh, kh, vt, attn);

    gemm_fin<<<dim3(8, 64), 256, 0, stream>>>(attn, WtO, bo, (float*)d_out);
}

// Round 15
// 223.189 us; speedup vs baseline: 1.0765x; 1.0765x over previous
//
#include <hip/hip_runtime.h>

#define BB 2
#define SS 2048
#define DD 1024
#define HH 16
#define DKK 64

typedef __attribute__((ext_vector_type(8))) short short8;
typedef __attribute__((ext_vector_type(4))) float floatx4;

__device__ inline float bf2f(ushort u) {
    union { unsigned int i; float f; } x; x.i = ((unsigned int)u) << 16; return x.f;
}
__device__ inline ushort f2bf(float f) {
    union { float f; unsigned int i; } x; x.f = f;
    unsigned int r = x.i + 0x7fff + ((x.i >> 16) & 1);
    return (ushort)(r >> 16);
}
__device__ inline void async_cp16(const ushort* g, ushort* l) {
    __builtin_amdgcn_global_load_lds(
        (const __attribute__((address_space(1))) unsigned int*)g,
        (__attribute__((address_space(3))) unsigned int*)l, 16, 0, 0);
}
// pack two f32 -> one dword of 2 bf16 (RNE), hw instruction
__device__ inline unsigned int cvt_pk_bf16(float lo, float hi) {
    unsigned int r;
    asm("v_cvt_pk_bf16_f32 %0, %1, %2" : "=v"(r) : "v"(lo), "v"(hi));
    return r;
}
// {a,b}: a.q2<->b.q0, a.q3<->b.q1  (16-lane groups = quads)
__device__ inline void swap32(unsigned int& a, unsigned int& b) {
    asm("v_permlane32_swap_b32 %0, %1" : "+v"(a), "+v"(b));
}
// {a,b}: a.q1<->b.q0, a.q3<->b.q2
__device__ inline void swap16(unsigned int& a, unsigned int& b) {
    asm("v_permlane16_swap_b32 %0, %1" : "+v"(a), "+v"(b));
}

// ---------- merged cast kernel: z=0..2 qkv fp32->bf16, z=3..4 weight T+cast --
__global__ __launch_bounds__(256) void cvt_all(const float* __restrict__ q,
                                               const float* __restrict__ k,
                                               const float* __restrict__ v,
                                               const float* __restrict__ w0,
                                               const float* __restrict__ w1,
                                               const float* __restrict__ w2,
                                               const float* __restrict__ w3,
                                               ushort* __restrict__ oq,
                                               ushort* __restrict__ ok,
                                               ushort* __restrict__ ov,
                                               ushort* __restrict__ t0,
                                               ushort* __restrict__ t1,
                                               ushort* __restrict__ t2,
                                               ushort* __restrict__ t3) {
    __shared__ ushort t[32][33];
    int z = blockIdx.z;
    if (z < 3) {
        const float* in = (z == 0) ? q : (z == 1) ? k : v;
        ushort* out = (z == 0) ? oq : (z == 1) ? ok : ov;
        int i = blockIdx.x * 256 + threadIdx.x;
        float4 f0 = ((const float4*)in)[i * 2];
        float4 f1 = ((const float4*)in)[i * 2 + 1];
        short8 p;
        p[0] = (short)f2bf(f0.x); p[1] = (short)f2bf(f0.y);
        p[2] = (short)f2bf(f0.z); p[3] = (short)f2bf(f0.w);
        p[4] = (short)f2bf(f1.x); p[5] = (short)f2bf(f1.y);
        p[6] = (short)f2bf(f1.z); p[7] = (short)f2bf(f1.w);
        ((short8*)out)[i] = p;
    } else {
        int m = (z - 3) * 2 + (blockIdx.x >> 10);     // matrix 0..3
        int tile = blockIdx.x & 1023;
        int bx = tile & 31, by = tile >> 5;
        const float* in = (m == 0) ? w0 : (m == 1) ? w1 : (m == 2) ? w2 : w3;
        ushort* out = (m == 0) ? t0 : (m == 1) ? t1 : (m == 2) ? t2 : t3;
        int tx = threadIdx.x & 31, ty = threadIdx.x >> 5;
        for (int i = ty; i < 32; i += 8)
            t[i][tx] = f2bf(in[(size_t)(by * 32 + i) * DD + bx * 32 + tx]);
        __syncthreads();
        for (int i = ty; i < 32; i += 8)
            out[(size_t)(bx * 32 + i) * DD + by * 32 + tx] = t[tx][i];
    }
}

// ---------- merged Q/K/V projection GEMM: 128x128 tile, 4 waves, BK=32 -------
// (R9-proven) counted vmcnt(4), raw s_barrier pair, XOR swizzle via
// pre-swizzled global source; 768 blocks = 3/CU.
__global__ __launch_bounds__(256, 3) void gemm_qkv(const ushort* __restrict__ Xq,
                                                   const ushort* __restrict__ Xk,
                                                   const ushort* __restrict__ Xv,
                                                   const ushort* __restrict__ WtQ,
                                                   const ushort* __restrict__ WtK,
                                                   const ushort* __restrict__ WtV,
                                                   const float* __restrict__ bq,
                                                   const float* __restrict__ bk,
                                                   const float* __restrict__ bv,
                                                   ushort* __restrict__ qh,
                                                   ushort* __restrict__ kh,
                                                   ushort* __restrict__ vt) {
    constexpr int K = 1024;
    constexpr int NKT = 32;
    __shared__ ushort smem[16384];           // 32 KB: 2 slots x (A 4096 + B 4096)

    int lin = blockIdx.x + ((blockIdx.y + (blockIdx.z << 5)) << 3);
    int wid = (lin & 7) * 96 + (lin >> 3);
    int z = wid >> 8;
    int rem = wid & 255;
    int byy = rem >> 3, bxx = rem & 7;
    int rowBase = byy * 128, colBase = bxx * 128;

    const ushort* Ag = (z == 0) ? Xq : (z == 1) ? Xk : Xv;
    const ushort* Bg = (z == 0) ? WtQ : (z == 1) ? WtK : WtV;
    const float* bias = (z == 0) ? bq : (z == 1) ? bk : bv;
    ushort* outp = (z == 0) ? qh : (z == 1) ? kh : vt;

    int tid = threadIdx.x;
    int wave = tid >> 6, lane = tid & 63, quad = lane >> 4, l15 = lane & 15;
    int wm = wave >> 1, wn = wave & 1;

    size_t srcA[2], srcB[2];
    int dstU[2];
#pragma unroll
    for (int r = 0; r < 2; ++r) {
        int lb = r * 4096 + wave * 1024 + lane * 16;
        int sl = lb ^ (((lb >> 9) & 1) << 5);
        int srow = sl >> 6;
        int scol = (sl & 63) >> 1;
        srcA[r] = (size_t)(rowBase + srow) * K + scol;
        srcB[r] = (size_t)(colBase + srow) * K + scol;
        dstU[r] = r * 2048 + wave * 512;
    }
    int aOff[4], bOff[4];
#pragma unroll
    for (int mi = 0; mi < 4; ++mi) {
        int row = wm * 64 + mi * 16 + l15;
        aOff[mi] = row * 32 + ((quad * 8) ^ (((row >> 3) & 1) << 4));
    }
#pragma unroll
    for (int ni = 0; ni < 4; ++ni) {
        int row = wn * 64 + ni * 16 + l15;
        bOff[ni] = 4096 + row * 32 + ((quad * 8) ^ (((row >> 3) & 1) << 4));
    }

    auto stageTile = [&](int u) {
        int slot = (u & 1) << 13;
        const ushort* As = Ag + u * 32;
        const ushort* Bs = Bg + u * 32;
        async_cp16(As + srcA[0], &smem[slot + dstU[0]]);
        async_cp16(As + srcA[1], &smem[slot + dstU[1]]);
        async_cp16(Bs + srcB[0], &smem[slot + 4096 + dstU[0]]);
        async_cp16(Bs + srcB[1], &smem[slot + 4096 + dstU[1]]);
    };

    floatx4 acc[4][4] = {};
    stageTile(0);
    for (int t = 0; t < NKT; ++t) {
        if (t < NKT - 1) {
            stageTile(t + 1);
            asm volatile("s_waitcnt vmcnt(4)" ::: "memory");
        } else {
            asm volatile("s_waitcnt vmcnt(0)" ::: "memory");
        }
        __builtin_amdgcn_s_barrier();
        __builtin_amdgcn_sched_barrier(0);
        int slot = (t & 1) << 13;
        short8 bfr[4], af[4];
#pragma unroll
        for (int ni = 0; ni < 4; ++ni)
            bfr[ni] = *(const short8*)&smem[slot + bOff[ni]];
#pragma unroll
        for (int mi = 0; mi < 4; ++mi)
            af[mi] = *(const short8*)&smem[slot + aOff[mi]];
#pragma unroll
        for (int mi = 0; mi < 4; ++mi)
#pragma unroll
            for (int ni = 0; ni < 4; ++ni)
                acc[mi][ni] = __builtin_amdgcn_mfma_f32_16x16x32_bf16(
                    af[mi], bfr[ni], acc[mi][ni], 0, 0, 0);
        __builtin_amdgcn_sched_barrier(0);
        __builtin_amdgcn_s_barrier();
    }

    float bvv[4];
#pragma unroll
    for (int ni = 0; ni < 4; ++ni)
        bvv[ni] = bias[colBase + wn * 64 + ni * 16 + l15];
    if (z == 2) {
#pragma unroll
        for (int mi = 0; mi < 4; ++mi)
#pragma unroll
            for (int ni = 0; ni < 4; ++ni) {
                int col = colBase + wn * 64 + ni * 16 + l15;
                int h = col >> 6, dk = col & 63;
                int rowg = rowBase + wm * 64 + mi * 16 + quad * 4;
                int b = rowg >> 11, s = rowg & 2047;
                int2 v;
                v.x = (int)cvt_pk_bf16(acc[mi][ni][0] + bvv[ni], acc[mi][ni][1] + bvv[ni]);
                v.y = (int)cvt_pk_bf16(acc[mi][ni][2] + bvv[ni], acc[mi][ni][3] + bvv[ni]);
                *(int2*)&outp[((size_t)((b * HH + h) * DKK + dk)) * SS + s] = v;
            }
    } else {
#pragma unroll
        for (int mi = 0; mi < 4; ++mi)
#pragma unroll
            for (int ni = 0; ni < 4; ++ni) {
                int col = colBase + wn * 64 + ni * 16 + l15;
                int h = col >> 6, dk = col & 63;
#pragma unroll
                for (int i = 0; i < 4; ++i) {
                    int rowg = rowBase + wm * 64 + mi * 16 + quad * 4 + i;
                    int b = rowg >> 11, s = rowg & 2047;
                    outp[((size_t)((b * HH + h) * SS + s)) * DKK + dk] =
                        f2bf(acc[mi][ni][i] + bvv[ni]);
                }
            }
    }
}

// ---------- final GEMM: 64x128 tile, counted-vmcnt schedule, fp32 out -------
__global__ __launch_bounds__(256, 2) void gemm_fin(const ushort* __restrict__ A,
                                                   const ushort* __restrict__ Bt,
                                                   const float* __restrict__ bias,
                                                   float* __restrict__ outp) {
    constexpr int K = 1024, N = 1024, NKT = 32;
    __shared__ ushort smem[12288];           // 24 KB: 2 slots x (A 2048 + B 4096)
    int tid = threadIdx.x;
    int wave = tid >> 6, lane = tid & 63, quad = lane >> 4, l15 = lane & 15;
    int wm = wave >> 1, wn = wave & 1;

    int lin = blockIdx.x + (blockIdx.y << 3);
    int wid = (lin & 7) * 64 + (lin >> 3);
    int bx = wid & 7, by = wid >> 3;
    int rowBase = by * 64, colBase = bx * 128;

    size_t srcA; int dstA;
    {
        int lb = wave * 1024 + lane * 16;
        int sl = lb ^ (((lb >> 9) & 1) << 5);
        srcA = (size_t)(rowBase + (sl >> 6)) * K + ((sl & 63) >> 1);
        dstA = wave * 512;
    }
    size_t srcB[2]; int dstB[2];
#pragma unroll
    for (int r = 0; r < 2; ++r) {
        int lb = r * 4096 + wave * 1024 + lane * 16;
        int sl = lb ^ (((lb >> 9) & 1) << 5);
        srcB[r] = (size_t)(colBase + (sl >> 6)) * K + ((sl & 63) >> 1);
        dstB[r] = 2048 + r * 2048 + wave * 512;
    }
    int aOff[2], bOff[4];
#pragma unroll
    for (int mi = 0; mi < 2; ++mi) {
        int row = wm * 32 + mi * 16 + l15;
        aOff[mi] = row * 32 + ((quad * 8) ^ (((row >> 3) & 1) << 4));
    }
#pragma unroll
    for (int ni = 0; ni < 4; ++ni) {
        int row = wn * 64 + ni * 16 + l15;
        bOff[ni] = 2048 + row * 32 + ((quad * 8) ^ (((row >> 3) & 1) << 4));
    }

    auto stageTile = [&](int u) {
        int slot = (u & 1) * 6144;
        const ushort* As = A + u * 32;
        const ushort* Bs = Bt + u * 32;
        async_cp16(As + srcA, &smem[slot + dstA]);
        async_cp16(Bs + srcB[0], &smem[slot + dstB[0]]);
        async_cp16(Bs + srcB[1], &smem[slot + dstB[1]]);
    };

    floatx4 acc[2][4] = {};
    stageTile(0);
    for (int t = 0; t < NKT; ++t) {
        if (t < NKT - 1) {
            stageTile(t + 1);
            asm volatile("s_waitcnt vmcnt(3)" ::: "memory");
        } else {
            asm volatile("s_waitcnt vmcnt(0)" ::: "memory");
        }
        __builtin_amdgcn_s_barrier();
        __builtin_amdgcn_sched_barrier(0);
        int slot = (t & 1) * 6144;
        short8 af[2], bfr[4];
#pragma unroll
        for (int ni = 0; ni < 4; ++ni)
            bfr[ni] = *(const short8*)&smem[slot + bOff[ni]];
#pragma unroll
        for (int mi = 0; mi < 2; ++mi)
            af[mi] = *(const short8*)&smem[slot + aOff[mi]];
#pragma unroll
        for (int mi = 0; mi < 2; ++mi)
#pragma unroll
            for (int ni = 0; ni < 4; ++ni)
                acc[mi][ni] = __builtin_amdgcn_mfma_f32_16x16x32_bf16(
                    af[mi], bfr[ni], acc[mi][ni], 0, 0, 0);
        __builtin_amdgcn_sched_barrier(0);
        __builtin_amdgcn_s_barrier();
    }
    for (int mi = 0; mi < 2; ++mi)
        for (int ni = 0; ni < 4; ++ni) {
            int col = colBase + wn * 64 + ni * 16 + l15;
            float bv = bias[col];
            for (int i = 0; i < 4; ++i) {
                int row = rowBase + wm * 32 + mi * 16 + quad * 4 + i;
                outp[(size_t)row * N + col] = acc[mi][ni][i] + bv;
            }
        }
}

// ---------- flash attention v5: paired tiles + setprio + XCD-chunked KV -----
__global__ __launch_bounds__(256, 2) void flash_attn5(const ushort* __restrict__ qh,
                                                      const ushort* __restrict__ kh,
                                                      const ushort* __restrict__ vt,
                                                      ushort* __restrict__ attn) {
    constexpr int LD = 72;
    __shared__ ushort Ksm[2][64 * LD];
    __shared__ ushort Vsm[2][64 * LD];
    int tid = threadIdx.x;
    int wave = tid >> 6, lane = tid & 63, quad = lane >> 4, l15 = lane & 15;

    // bijective XCD-chunked remap of the 512-block grid
    int lin = blockIdx.x + (blockIdx.y << 4) + (blockIdx.z << 8);
    int wid = (lin & 7) * 64 + (lin >> 3);
    const int qt0 = wid & 15;
    int h = (wid >> 4) & 15;
    int b = wid >> 8;
    const int qt1 = 31 - qt0;

    const size_t headQK = ((size_t)(b * HH + h)) * SS * DKK;
    const size_t headV  = ((size_t)(b * HH + h)) * DKK * SS;
    int c0 = tid, r0 = c0 >> 3, s0 = (c0 & 7) * 8;
    int c1 = tid + 256, r1 = c1 >> 3, s1 = (c1 & 7) * 8;

    int qrow0 = qt0 * 64 + wave * 16 + l15;
    int qrow1 = qt1 * 64 + wave * 16 + l15;
    short8 q0a = *(const short8*)&qh[headQK + (size_t)qrow0 * DKK + quad * 8];
    short8 q0b = *(const short8*)&qh[headQK + (size_t)qrow0 * DKK + 32 + quad * 8];
    short8 q1a = *(const short8*)&qh[headQK + (size_t)qrow1 * DKK + quad * 8];
    short8 q1b = *(const short8*)&qh[headQK + (size_t)qrow1 * DKK + 32 + quad * 8];

    floatx4 o0[4] = {}, o1[4] = {};
    float l0 = 0.f, l1 = 0.f;
    int qsel = wave * 16 + l15;

    *(int4*)&Ksm[0][r0 * LD + s0] = *(const int4*)&kh[headQK + (size_t)r0 * DKK + s0];
    *(int4*)&Ksm[0][r1 * LD + s1] = *(const int4*)&kh[headQK + (size_t)r1 * DKK + s1];
    *(int4*)&Vsm[0][r0 * LD + s0] = *(const int4*)&vt[headV + (size_t)r0 * SS + s0];
    *(int4*)&Vsm[0][r1 * LD + s1] = *(const int4*)&vt[headV + (size_t)r1 * SS + s1];
    __syncthreads();

    for (int kt = 0; kt <= qt1; ++kt) {
        int cur = kt & 1;
        bool pre = (kt < qt1);
        bool act0 = (kt <= qt0);
        int4 kA, kB, vA, vB;
        if (pre) {
            const ushort* kp = &kh[headQK + (size_t)((kt + 1) * 64) * DKK];
            const ushort* vp = &vt[headV + (kt + 1) * 64];
            kA = *(const int4*)&kp[(size_t)r0 * DKK + s0];
            kB = *(const int4*)&kp[(size_t)r1 * DKK + s1];
            vA = *(const int4*)&vp[(size_t)r0 * SS + s0];
            vB = *(const int4*)&vp[(size_t)r1 * SS + s1];
        }
        // swapped QK^T: S^T = K · Q^T for both tiles off shared K fragments
        floatx4 sv1[4], sv0[4];
        __builtin_amdgcn_s_setprio(1);
#pragma unroll
        for (int cn = 0; cn < 4; ++cn) {
            short8 kf0 = *(const short8*)&Ksm[cur][(cn * 16 + l15) * LD + quad * 8];
            short8 kf1 = *(const short8*)&Ksm[cur][(cn * 16 + l15) * LD + 32 + quad * 8];
            floatx4 zz = {};
            zz = __builtin_amdgcn_mfma_f32_16x16x32_bf16(kf0, q1a, zz, 0, 0, 0);
            zz = __builtin_amdgcn_mfma_f32_16x16x32_bf16(kf1, q1b, zz, 0, 0, 0);
            sv1[cn] = zz;
            if (act0) {
                floatx4 y = {};
                y = __builtin_amdgcn_mfma_f32_16x16x32_bf16(kf0, q0a, y, 0, 0, 0);
                y = __builtin_amdgcn_mfma_f32_16x16x32_bf16(kf1, q0b, y, 0, 0, 0);
                sv0[cn] = y;
            }
        }
        __builtin_amdgcn_s_setprio(0);
        short8 vf[2][4];
#pragma unroll
        for (int ks = 0; ks < 2; ++ks)
#pragma unroll
            for (int n = 0; n < 4; ++n)
                vf[ks][n] = *(const short8*)&Vsm[cur][(n * 16 + l15) * LD + ks * 32 + quad * 8];

        {
            bool diag = (kt == qt1);
            unsigned int pkd[4][2];
#pragma unroll
            for (int cn = 0; cn < 4; ++cn) {
#pragma unroll
                for (int i = 0; i < 4; ++i) {
                    float p = __expf(sv1[cn][i] * 0.125f);
                    if (diag && (cn * 16 + quad * 4 + i) > qsel) p = 0.f;
                    sv1[cn][i] = p;
                    l1 += p;
                }
                pkd[cn][0] = cvt_pk_bf16(sv1[cn][0], sv1[cn][1]);
                pkd[cn][1] = cvt_pk_bf16(sv1[cn][2], sv1[cn][3]);
            }
            __builtin_amdgcn_s_setprio(1);
#pragma unroll
            for (int ks = 0; ks < 2; ++ks) {
                unsigned int a0 = pkd[ks * 2][0], b0 = pkd[ks * 2 + 1][0];
                swap32(a0, b0); swap16(a0, b0);
                unsigned int a1 = pkd[ks * 2][1], b1 = pkd[ks * 2 + 1][1];
                swap32(a1, b1); swap16(a1, b1);
                union { int4 i4; short8 s8; } u;
                u.i4 = make_int4((int)a0, (int)a1, (int)b0, (int)b1);
#pragma unroll
                for (int n = 0; n < 4; ++n)
                    o1[n] = __builtin_amdgcn_mfma_f32_16x16x32_bf16(
                        vf[ks][n], u.s8, o1[n], 0, 0, 0);
            }
            __builtin_amdgcn_s_setprio(0);
        }
        if (act0) {
            bool diag = (kt == qt0);
            unsigned int pkd[4][2];
#pragma unroll
            for (int cn = 0; cn < 4; ++cn) {
#pragma unroll
                for (int i = 0; i < 4; ++i) {
                    float p = __expf(sv0[cn][i] * 0.125f);
                    if (diag && (cn * 16 + quad * 4 + i) > qsel) p = 0.f;
                    sv0[cn][i] = p;
                    l0 += p;
                }
                pkd[cn][0] = cvt_pk_bf16(sv0[cn][0], sv0[cn][1]);
                pkd[cn][1] = cvt_pk_bf16(sv0[cn][2], sv0[cn][3]);
            }
            __builtin_amdgcn_s_setprio(1);
#pragma unroll
            for (int ks = 0; ks < 2; ++ks) {
                unsigned int a0 = pkd[ks * 2][0], b0 = pkd[ks * 2 + 1][0];
                swap32(a0, b0); swap16(a0, b0);
                unsigned int a1 = pkd[ks * 2][1], b1 = pkd[ks * 2 + 1][1];
                swap32(a1, b1); swap16(a1, b1);
                union { int4 i4; short8 s8; } u;
                u.i4 = make_int4((int)a0, (int)a1, (int)b0, (int)b1);
#pragma unroll
                for (int n = 0; n < 4; ++n)
                    o0[n] = __builtin_amdgcn_mfma_f32_16x16x32_bf16(
                        vf[ks][n], u.s8, o0[n], 0, 0, 0);
            }
            __builtin_amdgcn_s_setprio(0);
        }
        if (pre) {
            int nb = cur ^ 1;
            *(int4*)&Ksm[nb][r0 * LD + s0] = kA;
            *(int4*)&Ksm[nb][r1 * LD + s1] = kB;
            *(int4*)&Vsm[nb][r0 * LD + s0] = vA;
            *(int4*)&Vsm[nb][r1 * LD + s1] = vB;
        }
        __syncthreads();
    }
    l0 += __shfl_xor(l0, 16, 64); l0 += __shfl_xor(l0, 32, 64);
    l1 += __shfl_xor(l1, 16, 64); l1 += __shfl_xor(l1, 32, 64);
    float inv0 = 1.0f / l0, inv1 = 1.0f / l1;
    size_t rowOff0 = ((size_t)(b * SS + qt0 * 64 + wave * 16 + l15)) * DD + h * 64;
    size_t rowOff1 = ((size_t)(b * SS + qt1 * 64 + wave * 16 + l15)) * DD + h * 64;
#pragma unroll
    for (int n = 0; n < 4; ++n) {
        int dof = n * 16 + quad * 4;
        int2 v0, v1;
        v0.x = (int)cvt_pk_bf16(o0[n][0] * inv0, o0[n][1] * inv0);
        v0.y = (int)cvt_pk_bf16(o0[n][2] * inv0, o0[n][3] * inv0);
        v1.x = (int)cvt_pk_bf16(o1[n][0] * inv1, o1[n][1] * inv1);
        v1.y = (int)cvt_pk_bf16(o1[n][2] * inv1, o1[n][3] * inv1);
        *(int2*)&attn[rowOff0 + dof] = v0;
        *(int2*)&attn[rowOff1 + dof] = v1;
    }
}

extern "C" void kernel_launch(void* const* d_in, const int* in_sizes, int n_in,
                              void* d_out, int out_size, void* d_ws, size_t ws_size,
                              hipStream_t stream) {
    const float* q  = (const float*)d_in[0];
    const float* k  = (const float*)d_in[1];
    const float* v  = (const float*)d_in[2];
    // d_in[3] = causal mask (deterministic) -> not read
    const float* Wq = (const float*)d_in[4];
    const float* bq = (const float*)d_in[5];
    const float* Wk = (const float*)d_in[6];
    const float* bk = (const float*)d_in[7];
    const float* Wv = (const float*)d_in[8];
    const float* bv = (const float*)d_in[9];
    const float* Wo = (const float*)d_in[10];
    const float* bo = (const float*)d_in[11];

    // ws (40 MB): [WtQ|WtK|WtV|WtO 2MB each][Xv 8][qh 8][kh 8][vt 8]
    // d_out (16 MB fp32) doubles as [Xq 8][Xk 8] bf16 staging until gemm_fin.
    ushort* ws   = (ushort*)d_ws;
    ushort* WtQ  = ws;
    ushort* WtK  = WtQ + (1u << 20);
    ushort* WtV  = WtK + (1u << 20);
    ushort* WtO  = WtV + (1u << 20);
    ushort* Xv   = WtO + (1u << 20);
    ushort* qh   = Xv + (4u << 20);
    ushort* kh   = qh + (4u << 20);
    ushort* vt   = kh + (4u << 20);
    ushort* Xq   = (ushort*)d_out;
    ushort* Xk   = Xq + (4u << 20);
    ushort* attn = Xv;                 // Xv dead after gemm_qkv

    cvt_all<<<dim3(2048, 1, 5), 256, 0, stream>>>(q, k, v, Wq, Wk, Wv, Wo,
                                                  Xq, Xk, Xv,
                                                  WtQ, WtK, WtV, WtO);

    gemm_qkv<<<dim3(8, 32, 3), 256, 0, stream>>>(Xq, Xk, Xv, WtQ, WtK, WtV,
                                                 bq, bk, bv, qh, kh, vt);

    flash_attn5<<<dim3(16, 16, 2), 256, 0, stream>>>(qh, kh, vt, attn);

    gemm_fin<<<dim3(8, 64), 256, 0, stream>>>(attn, WtO, bo, (float*)d_out);
}